// Round 15
// baseline (4872.400 us; speedup 1.0000x reference)
//
#include <hip/hip_runtime.h>
#include <hip/hip_bf16.h>

#define NCL   300000
#define NLIT  200000
#define HALFL 100000
#define NVAR  100000

#define NB_C  293            // 293*1024 = 300032 >= NCL
#define PAD_C (NB_C*1024)
#define NB_L  196            // 196*1024 = 200704 >= NLIT
#define PAD_L (NB_L*1024)

#define CGRID  1563          // clause blocks; 1563*192 = 300,096 >= NCL
#define CTPB   3             // contiguous 64-row tiles per block
#define PHALF  (CGRID*128)   // 200,064: offset of sumsq plane in part

typedef __attribute__((ext_vector_type(8))) short short8;   // 8 bf16 (4 VGPRs)
typedef __attribute__((ext_vector_type(4))) float f32x4;    // MFMA acc

__device__ __forceinline__ unsigned short f2b(float x){     // fp32 -> bf16 RNE
  union{float f; unsigned int u;} v; v.f = x;
  unsigned int r = v.u + 0x7FFF + ((v.u >> 16) & 1);
  return (unsigned short)(r >> 16);
}
__device__ __forceinline__ float b2f(unsigned short u){
  union{unsigned int i; float f;} x; x.i = ((unsigned int)u) << 16; return x.f;
}
__device__ __forceinline__ int imax(int a, int b){ return a > b ? a : b; }

// Lh uses PAIRED layout: Lvar[v][0..127] = lit v, Lvar[v][128..255] = lit v+HALFL.

// ---------------------------------------------------------------- utilities
__global__ void k_init_lh4(const float4* __restrict__ L04, float4* __restrict__ Lh4){
  int i = blockIdx.x*256 + threadIdx.x;            // 6,400,000 float4
  Lh4[i] = L04[i & 31];                            // (4i)&127 == 4*(i&31): exact
}

__global__ void k_zero4(float4* __restrict__ p, int n4){
  int i = blockIdx.x*256 + threadIdx.x;
  if(i < n4) p[i] = make_float4(0.f,0.f,0.f,0.f);
}

// Pack fp32 row-major W[K][N] into hi/lo bf16 MFMA B-fragment order
__global__ void k_pack_w(const float* __restrict__ W, short* __restrict__ Whi,
                         short* __restrict__ Wlo, int K, int N){
  int i = blockIdx.x*256 + threadIdx.x;
  if(i >= K*N) return;
  int j  = i & 7;
  int L  = (i >> 3) & 63;
  int kt = (i >> 9) % (K >> 5);
  int nt = (i >> 9) / (K >> 5);
  int k = kt*32 + ((L >> 4) << 3) + j;
  int n = nt*16 + (L & 15);
  float w = W[(size_t)k*N + n];
  unsigned short hi = f2b(w);
  Whi[i] = (short)hi;
  Wlo[i] = (short)f2b(w - b2f(hi));
}

// ---------------------------------------------------------------- CSR build
__global__ __launch_bounds__(256) void k_hist(const int* __restrict__ ci, const int* __restrict__ li,
    int* __restrict__ Pc, int* __restrict__ Pl, int ne){
  int e = blockIdx.x*256 + threadIdx.x;
  if(e < ne){ atomicAdd(&Pc[ci[e]], 1); atomicAdd(&Pl[li[e]], 1); }
}

__global__ __launch_bounds__(256) void k_scan_pass1(const int* __restrict__ P, int* __restrict__ psum){
  __shared__ int red[256];
  int t = threadIdx.x;
  int4 v = *(const int4*)&P[blockIdx.x*1024 + t*4];
  red[t] = v.x + v.y + v.z + v.w;
  __syncthreads();
  for(int ofs=128; ofs>0; ofs>>=1){
    if(t < ofs) red[t] += red[t+ofs];
    __syncthreads();
  }
  if(t == 0) psum[blockIdx.x] = red[0];
}

__global__ __launch_bounds__(512) void k_scan_pass2(int* __restrict__ psum, int nb){
  __shared__ int sA[512], sB[512];
  int t = threadIdx.x;
  sA[t] = (t < nb) ? psum[t] : 0;
  __syncthreads();
  int* src = sA; int* dst = sB;
  for(int ofs=1; ofs<512; ofs<<=1){
    int x = src[t];
    if(t >= ofs) x += src[t-ofs];
    dst[t] = x;
    __syncthreads();
    int* tmp = src; src = dst; dst = tmp;
  }
  psum[t] = t ? src[t-1] : 0;    // exclusive
}

__global__ __launch_bounds__(256) void k_scan_pass3(int* __restrict__ P, const int* __restrict__ psum){
  __shared__ int sA[256], sB[256];
  int t = threadIdx.x;
  int base = blockIdx.x*1024 + t*4;
  int4 v = *(const int4*)&P[base];
  int tsum = v.x + v.y + v.z + v.w;
  sA[t] = tsum;
  __syncthreads();
  int* src = sA; int* dst = sB;
  for(int ofs=1; ofs<256; ofs<<=1){
    int x = src[t];
    if(t >= ofs) x += src[t-ofs];
    dst[t] = x;
    __syncthreads();
    int* tmp = src; src = dst; dst = tmp;
  }
  int excl = psum[blockIdx.x] + src[t] - tsum;
  int4 o;
  o.x = excl;
  o.y = o.x + v.x;
  o.z = o.y + v.y;
  o.w = o.z + v.z;
  *(int4*)&P[base] = o;
}

// After k_fill, P[c] holds END offset of row c; begin(c) = c ? P[c-1] : 0.
__global__ __launch_bounds__(256) void k_fill(const int* __restrict__ ci, const int* __restrict__ li,
    int* __restrict__ Pc, int* __restrict__ Pl, int* __restrict__ clit, int* __restrict__ lcl, int ne){
  int e = blockIdx.x*256 + threadIdx.x;
  if(e < ne){
    int c = ci[e], l = li[e];
    clit[atomicAdd(&Pc[c], 1)] = e;
    lcl [atomicAdd(&Pl[l], 1)] = e;
  }
}

// Canonicalize each row slice: sort edge ids ascending, then map to PACKED offsets.
// mode 0 (clause side): lit l -> Lvar offset (v<<8 | s*128)
// mode 1 (lit side):    clause c -> C row offset (c<<7)
__global__ __launch_bounds__(256) void k_sortmap(const int* __restrict__ P,
    int* __restrict__ slots, const int* __restrict__ map, int nrows, int mode){
  int r = blockIdx.x*256 + threadIdx.x;
  if(r >= nrows) return;
  int b = r ? P[r-1] : 0;
  int e = P[r];
  for(int i=b; i<e-1; i++){
    int mi = i, mv = slots[i];
    for(int j=i+1; j<e; j++){ int v = slots[j]; if(v < mv){ mv = v; mi = j; } }
    slots[mi] = slots[i]; slots[i] = mv;
  }
  for(int i=b; i<e; i++){
    int l = map[slots[i]];
    slots[i] = mode ? (l << 7)
                    : ((l < HALFL) ? (l << 8) : (((l - HALFL) << 8) | 128));
  }
}

// ------ clause side: CSR gather + COMPENSATED bf16 MFMA MLP 256->256->128
// 512 thr, 3 CONTIGUOUS 64-row tiles per block (grid 1563) -> cache behavior
// identical to champion's contiguous sweep. FUSED column stats: per-thread
// accumulation in fixed (tile,rt,reg) order -> one butterfly -> one EXCLUSIVE
// part slot per block. No atomics anywhere -> replay-deterministic.
__global__ __launch_bounds__(512, 4) void k_clause_fused(
    const int* __restrict__ Pc, const int* __restrict__ clit,
    const float* __restrict__ Lh,
    const short* __restrict__ W1h, const short* __restrict__ W1l, const float* __restrict__ b1,
    const short* __restrict__ W2h, const short* __restrict__ W2l, const float* __restrict__ b2,
    float* __restrict__ Y, float* __restrict__ part){
  __shared__ short xs[2][64][264];
  __shared__ int rng[65];
  const int t = threadIdx.x;
  const int lane = t & 63, wv = t >> 6;
  const int c16 = lane & 15;
  const int ak  = (lane >> 4) * 8;
  float csum = 0.f, csqs = 0.f;

  for(int tile = 0; tile < CTPB; tile++){
    const int r0 = blockIdx.x * 192 + tile * 64;
    if(t < 65){
      int q = r0 + t;                      // q can reach 300,096 > NCL: clamp
      rng[t] = q ? Pc[(q <= NCL ? q : NCL) - 1] : 0;
    }
    __syncthreads();

    { // gather: lanes 0-31 direct half, 32-63 flipped; 1 contiguous KB per row
      const int hxor = (lane >> 5) << 7;   // 0 / 128: selects Lvar half
      const int f4 = (lane & 31) * 4;
      const int rb = wv*8;
      int eb[8], dd[8];
      #pragma unroll
      for(int i=0;i<8;i++){ eb[i]=rng[rb+i]; dd[i]=rng[rb+i+1]-eb[i]; }
      int md = 0;
      #pragma unroll
      for(int i=0;i<8;i++) md = imax(md, dd[i]);
      float4 a[8];
      int li[8];
      #pragma unroll
      for(int i=0;i<8;i++){ a[i]=make_float4(0.f,0.f,0.f,0.f); li[i]=(dd[i]>0)?clit[eb[i]]:0; }
      for(int s=0; s<md; s++){
        float4 v[8];
        #pragma unroll
        for(int i=0;i<8;i++) v[i] = *(const float4*)&Lh[(size_t)((li[i] ^ hxor) + f4)];
        int p[8];
        #pragma unroll
        for(int i=0;i<8;i++) p[i] = (s+1<dd[i]) ? clit[eb[i]+s+1] : 0;
        #pragma unroll
        for(int i=0;i<8;i++){
          float m = (s<dd[i]) ? 1.f : 0.f;
          a[i].x=fmaf(m,v[i].x,a[i].x); a[i].y=fmaf(m,v[i].y,a[i].y);
          a[i].z=fmaf(m,v[i].z,a[i].z); a[i].w=fmaf(m,v[i].w,a[i].w);
          li[i]=p[i];
        }
      }
      #pragma unroll
      for(int i=0;i<8;i++){
        float4 aa = a[i];
        unsigned short hx=f2b(aa.x), hy=f2b(aa.y), hz=f2b(aa.z), hw=f2b(aa.w);
        unsigned short lx=f2b(aa.x-b2f(hx)), ly=f2b(aa.y-b2f(hy));
        unsigned short lz=f2b(aa.z-b2f(hz)), lw=f2b(aa.w-b2f(hw));
        *(uint2*)&xs[0][rb+i][hxor + f4] =
          make_uint2(((unsigned int)hy<<16)|hx, ((unsigned int)hw<<16)|hz);
        *(uint2*)&xs[1][rb+i][hxor + f4] =
          make_uint2(((unsigned int)ly<<16)|lx, ((unsigned int)lw<<16)|lz);
      }
    }
    __syncthreads();

    // layer 1: 256 -> 256; wave owns nt = wv*2+ntl for ALL 4 row tiles
    f32x4 acc[4][2];
    #pragma unroll
    for(int ntl=0; ntl<2; ntl++){
      float bv = b1[(wv*2+ntl)*16 + c16];
      #pragma unroll
      for(int rt=0; rt<4; rt++) acc[rt][ntl] = (f32x4){bv, bv, bv, bv};
    }
    {
      const short8* Bh = (const short8*)W1h;
      const short8* Bl = (const short8*)W1l;
      #pragma unroll
      for(int kt=0; kt<8; kt++){
        short8 ah[4], al[4];
        #pragma unroll
        for(int rt=0; rt<4; rt++){
          ah[rt] = *(const short8*)&xs[0][rt*16 + c16][kt*32 + ak];
          al[rt] = *(const short8*)&xs[1][rt*16 + c16][kt*32 + ak];
        }
        #pragma unroll
        for(int ntl=0; ntl<2; ntl++){
          int g = wv*2 + ntl;
          short8 bh = Bh[(g*8 + kt)*64 + lane];
          short8 bl = Bl[(g*8 + kt)*64 + lane];
          #pragma unroll
          for(int rt=0; rt<4; rt++){
            acc[rt][ntl] = __builtin_amdgcn_mfma_f32_16x16x32_bf16(ah[rt], bh, acc[rt][ntl], 0, 0, 0);
            acc[rt][ntl] = __builtin_amdgcn_mfma_f32_16x16x32_bf16(ah[rt], bl, acc[rt][ntl], 0, 0, 0);
            acc[rt][ntl] = __builtin_amdgcn_mfma_f32_16x16x32_bf16(al[rt], bh, acc[rt][ntl], 0, 0, 0);
          }
        }
      }
    }
    __syncthreads();
    #pragma unroll
    for(int rt=0; rt<4; rt++){
      #pragma unroll
      for(int ntl=0; ntl<2; ntl++){
        int col = (wv*2 + ntl)*16 + c16;
        int rowb = rt*16 + ((lane >> 4) << 2);
        #pragma unroll
        for(int reg=0; reg<4; reg++){
          float v = fmaxf(acc[rt][ntl][reg], 0.f);
          unsigned short hi = f2b(v);
          xs[0][rowb + reg][col] = (short)hi;
          xs[1][rowb + reg][col] = (short)f2b(v - b2f(hi));
        }
      }
    }
    __syncthreads();

    // layer 2: 256 -> 128; wave owns nt = wv for ALL 4 row tiles
    f32x4 o4[4];
    {
      float bv = b2[wv*16 + c16];
      #pragma unroll
      for(int rt=0; rt<4; rt++) o4[rt] = (f32x4){bv, bv, bv, bv};
    }
    {
      const short8* Bh = (const short8*)W2h;
      const short8* Bl = (const short8*)W2l;
      #pragma unroll
      for(int kt=0; kt<8; kt++){
        short8 ah[4], al[4];
        #pragma unroll
        for(int rt=0; rt<4; rt++){
          ah[rt] = *(const short8*)&xs[0][rt*16 + c16][kt*32 + ak];
          al[rt] = *(const short8*)&xs[1][rt*16 + c16][kt*32 + ak];
        }
        short8 bh = Bh[(wv*8 + kt)*64 + lane];
        short8 bl = Bl[(wv*8 + kt)*64 + lane];
        #pragma unroll
        for(int rt=0; rt<4; rt++){
          o4[rt] = __builtin_amdgcn_mfma_f32_16x16x32_bf16(ah[rt], bh, o4[rt], 0, 0, 0);
          o4[rt] = __builtin_amdgcn_mfma_f32_16x16x32_bf16(ah[rt], bl, o4[rt], 0, 0, 0);
          o4[rt] = __builtin_amdgcn_mfma_f32_16x16x32_bf16(al[rt], bh, o4[rt], 0, 0, 0);
        }
      }
    }
    // Y store + per-thread column-stat accumulation (fixed order)
    {
      const int col = wv*16 + c16;
      #pragma unroll
      for(int rt=0; rt<4; rt++){
        int rowb = r0 + rt*16 + ((lane >> 4) << 2);
        #pragma unroll
        for(int reg=0; reg<4; reg++){
          int rr = rowb + reg;
          if(rr < NCL){
            float v = o4[rt][reg];
            Y[(size_t)rr*128 + col] = v;
            csum += v;
            csqs = fmaf(v, v, csqs);
          }
        }
      }
    }
    __syncthreads();   // xs/rng reads done before next tile overwrites
  }

  // combine the 4 row-bands (lanes differing in bits 4..5) + exclusive store
  csum += __shfl_xor(csum, 16, 64); csum += __shfl_xor(csum, 32, 64);
  csqs += __shfl_xor(csqs, 16, 64); csqs += __shfl_xor(csqs, 32, 64);
  if(lane < 16){
    part[blockIdx.x*128 + wv*16 + c16] = csum;
    part[PHALF + blockIdx.x*128 + wv*16 + c16] = csqs;
  }
}

// Reduce 1563 partials per column in fixed strided order -> mean, 1/(std+eps).
__global__ __launch_bounds__(512) void k_finstats(const float* __restrict__ part, float* __restrict__ st){
  __shared__ float red[2][512];
  const int t = threadIdx.x, j = t & 127, h = t >> 7;   // h in 0..3
  float s = 0.f, s2 = 0.f;
  for(int b = h; b < CGRID; b += 4){
    s  += part[b*128 + j];
    s2 += part[PHALF + b*128 + j];
  }
  red[0][t] = s; red[1][t] = s2; __syncthreads();
  if(t < 128){
    float S  = red[0][j] + red[0][j+128] + red[0][j+256] + red[0][j+384];
    float S2 = red[1][j] + red[1][j+128] + red[1][j+256] + red[1][j+384];
    const float n = (float)NCL;
    float mean = S/n;
    float var = (S2 - n*mean*mean) / (n - 1.f);   // ddof=1
    var = fmaxf(var, 0.f);
    st[256+j] = mean;
    st[384+j] = 1.f/(sqrtf(var) + 1e-10f);
  }
}

// -- literal side: gather(normalized) + COMPENSATED bf16 MFMA 128->128->128
//    + 0.1*residual + LayerNorm. 256 thr, 32 lits/block. (R14-champion verbatim)
__global__ __launch_bounds__(256) void k_lit_fused(
    const int* __restrict__ Pl, const int* __restrict__ lcl,
    const float* __restrict__ C, const float* __restrict__ st,
    const short* __restrict__ W1h, const short* __restrict__ W1l, const float* __restrict__ b1,
    const short* __restrict__ W2h, const short* __restrict__ W2l, const float* __restrict__ b2,
    const float* __restrict__ lng, const float* __restrict__ lnb, float* __restrict__ Lh){
  __shared__ short xs[2][32][136];
  __shared__ int rng[33];
  float* ys = (float*)&xs[0][0][0];          // [32][132] fp32, aliases xs
  const int t = threadIdx.x;
  const int r0 = blockIdx.x * 32;
  const int sflag = (r0 >= HALFL) ? 1 : 0;               // Lvar half
  const size_t vb = (size_t)(r0 - (sflag ? HALFL : 0));  // Lvar base row

  if(t < 33) rng[t] = (r0 + t == 0) ? 0 : Pl[r0 + t - 1];
  __syncthreads();

  const int lane = t & 63, wv = t >> 6;
  { // gather: half-wave rows wv*8+half*4 .. +3, interleaved; f4/lane covers 128
    const int half = lane >> 5, f4 = (lane & 31) * 4;
    float4 mean4 = *(const float4*)&st[256+f4];
    float4 isd4  = *(const float4*)&st[384+f4];
    const int rb4 = wv*8 + half*4;
    const int e0=rng[rb4+0], d0=rng[rb4+1]-e0;
    const int e1=rng[rb4+1], d1=rng[rb4+2]-e1;
    const int e2=rng[rb4+2], d2=rng[rb4+3]-e2;
    const int e3=rng[rb4+3], d3=rng[rb4+4]-e3;
    float4 a0=make_float4(0.f,0.f,0.f,0.f), a1=a0, a2=a0, a3=a0;
    int l0=(d0>0)?lcl[e0]:0, l1=(d1>0)?lcl[e1]:0;
    int l2=(d2>0)?lcl[e2]:0, l3=(d3>0)?lcl[e3]:0;
    const int md = imax(imax(d0,d1), imax(d2,d3));
    for(int s=0; s<md; s++){
      float4 v0 = *(const float4*)&C[(size_t)l0 + f4];   // lcl pre-scaled c<<7
      float4 v1 = *(const float4*)&C[(size_t)l1 + f4];
      float4 v2 = *(const float4*)&C[(size_t)l2 + f4];
      float4 v3 = *(const float4*)&C[(size_t)l3 + f4];
      int p0=(s+1<d0)?lcl[e0+s+1]:0;
      int p1=(s+1<d1)?lcl[e1+s+1]:0;
      int p2=(s+1<d2)?lcl[e2+s+1]:0;
      int p3=(s+1<d3)?lcl[e3+s+1]:0;
      float m0=(s<d0)?1.f:0.f, m1=(s<d1)?1.f:0.f;
      float m2=(s<d2)?1.f:0.f, m3=(s<d3)?1.f:0.f;
      a0.x=fmaf(m0,v0.x,a0.x); a0.y=fmaf(m0,v0.y,a0.y); a0.z=fmaf(m0,v0.z,a0.z); a0.w=fmaf(m0,v0.w,a0.w);
      a1.x=fmaf(m1,v1.x,a1.x); a1.y=fmaf(m1,v1.y,a1.y); a1.z=fmaf(m1,v1.z,a1.z); a1.w=fmaf(m1,v1.w,a1.w);
      a2.x=fmaf(m2,v2.x,a2.x); a2.y=fmaf(m2,v2.y,a2.y); a2.z=fmaf(m2,v2.z,a2.z); a2.w=fmaf(m2,v2.w,a2.w);
      a3.x=fmaf(m3,v3.x,a3.x); a3.y=fmaf(m3,v3.y,a3.y); a3.z=fmaf(m3,v3.z,a3.z); a3.w=fmaf(m3,v3.w,a3.w);
      l0=p0; l1=p1; l2=p2; l3=p3;
    }
    float4 aa[4] = {a0, a1, a2, a3};
    float dd[4] = {(float)d0, (float)d1, (float)d2, (float)d3};
    #pragma unroll
    for(int i=0;i<4;i++){
      float4 a = aa[i];
      float dg = dd[i];
      a.x = (a.x - dg*mean4.x)*isd4.x; a.y = (a.y - dg*mean4.y)*isd4.y;
      a.z = (a.z - dg*mean4.z)*isd4.z; a.w = (a.w - dg*mean4.w)*isd4.w;
      unsigned short hx=f2b(a.x), hy=f2b(a.y), hz=f2b(a.z), hw=f2b(a.w);
      unsigned short lx=f2b(a.x-b2f(hx)), ly=f2b(a.y-b2f(hy));
      unsigned short lz=f2b(a.z-b2f(hz)), lw=f2b(a.w-b2f(hw));
      *(uint2*)&xs[0][rb4+i][f4] = make_uint2(((unsigned int)hy<<16)|hx, ((unsigned int)hw<<16)|hz);
      *(uint2*)&xs[1][rb4+i][f4] = make_uint2(((unsigned int)ly<<16)|lx, ((unsigned int)lw<<16)|lz);
    }
  }
  __syncthreads();

  const int c16 = lane & 15;
  const int ak  = (lane >> 4) * 8;
  const int am0 = c16, am1 = 16 + c16;

  // layer 1: 128 -> 128; wave owns nt = wv*2+ntl for BOTH row tiles
  f32x4 acc[2][2];                        // [rt][ntl]
  #pragma unroll
  for(int ntl=0; ntl<2; ntl++){
    float bv = b1[(wv*2+ntl)*16 + c16];
    acc[0][ntl] = (f32x4){bv, bv, bv, bv};
    acc[1][ntl] = acc[0][ntl];
  }
  {
    const short8* Bh = (const short8*)W1h;
    const short8* Bl = (const short8*)W1l;
    #pragma unroll
    for(int kt=0; kt<4; kt++){
      short8 ah0 = *(const short8*)&xs[0][am0][kt*32 + ak];
      short8 al0 = *(const short8*)&xs[1][am0][kt*32 + ak];
      short8 ah1 = *(const short8*)&xs[0][am1][kt*32 + ak];
      short8 al1 = *(const short8*)&xs[1][am1][kt*32 + ak];
      #pragma unroll
      for(int ntl=0; ntl<2; ntl++){
        int g = wv*2 + ntl;
        short8 bh = Bh[(g*4 + kt)*64 + lane];
        short8 bl = Bl[(g*4 + kt)*64 + lane];
        acc[0][ntl] = __builtin_amdgcn_mfma_f32_16x16x32_bf16(ah0, bh, acc[0][ntl], 0, 0, 0);
        acc[0][ntl] = __builtin_amdgcn_mfma_f32_16x16x32_bf16(ah0, bl, acc[0][ntl], 0, 0, 0);
        acc[0][ntl] = __builtin_amdgcn_mfma_f32_16x16x32_bf16(al0, bh, acc[0][ntl], 0, 0, 0);
        acc[1][ntl] = __builtin_amdgcn_mfma_f32_16x16x32_bf16(ah1, bh, acc[1][ntl], 0, 0, 0);
        acc[1][ntl] = __builtin_amdgcn_mfma_f32_16x16x32_bf16(ah1, bl, acc[1][ntl], 0, 0, 0);
        acc[1][ntl] = __builtin_amdgcn_mfma_f32_16x16x32_bf16(al1, bh, acc[1][ntl], 0, 0, 0);
      }
    }
  }
  __syncthreads();
  // hidden: ReLU -> hi/lo bf16, overwrite xs
  #pragma unroll
  for(int rt=0; rt<2; rt++){
    #pragma unroll
    for(int ntl=0; ntl<2; ntl++){
      int col = (wv*2 + ntl)*16 + c16;
      int rowb = rt*16 + ((lane >> 4) << 2);
      #pragma unroll
      for(int reg=0; reg<4; reg++){
        float v = fmaxf(acc[rt][ntl][reg], 0.f);
        unsigned short hi = f2b(v);
        xs[0][rowb + reg][col] = (short)hi;
        xs[1][rowb + reg][col] = (short)f2b(v - b2f(hi));
      }
    }
  }
  __syncthreads();

  // layer 2: 128 -> 128 (A-frags loaded upfront, then xs is reused as ys)
  const int rt  = wv & 1;
  const int ntb = (wv >> 1) * 4;
  const int am  = rt*16 + c16;
  short8 a2h[4], a2l[4];
  #pragma unroll
  for(int kt=0; kt<4; kt++){
    a2h[kt] = *(const short8*)&xs[0][am][kt*32 + ak];
    a2l[kt] = *(const short8*)&xs[1][am][kt*32 + ak];
  }
  __syncthreads();                         // all xs reads done -> ys writable
  f32x4 o4[4];
  #pragma unroll
  for(int ntl=0; ntl<4; ntl++){
    float bv = b2[(ntb+ntl)*16 + c16];
    o4[ntl] = (f32x4){bv, bv, bv, bv};
  }
  {
    const short8* Bh = (const short8*)W2h;
    const short8* Bl = (const short8*)W2l;
    #pragma unroll
    for(int kt=0; kt<4; kt++){
      #pragma unroll
      for(int ntl=0; ntl<4; ntl++){
        int g = ntb + ntl;
        short8 bh = Bh[(g*4 + kt)*64 + lane];
        short8 bl = Bl[(g*4 + kt)*64 + lane];
        o4[ntl] = __builtin_amdgcn_mfma_f32_16x16x32_bf16(a2h[kt], bh, o4[ntl], 0, 0, 0);
        o4[ntl] = __builtin_amdgcn_mfma_f32_16x16x32_bf16(a2h[kt], bl, o4[ntl], 0, 0, 0);
        o4[ntl] = __builtin_amdgcn_mfma_f32_16x16x32_bf16(a2l[kt], bh, o4[ntl], 0, 0, 0);
      }
    }
  }
  #pragma unroll
  for(int ntl=0; ntl<4; ntl++){
    int col = (ntb + ntl)*16 + c16;
    int rowb = rt*16 + ((lane >> 4) << 2);
    #pragma unroll
    for(int reg=0; reg<4; reg++)
      ys[(rowb + reg)*132 + col] = o4[ntl][reg];
  }
  __syncthreads();

  { // residual + LayerNorm: 8 threads per row, 16 cols each; Lvar addressing
    const int r  = t >> 3;                 // 0..31
    const int cg = (t & 7) * 16;
    const size_t base = (vb + r)*256 + sflag*128;
    float y[16];
    #pragma unroll
    for(int jj=0; jj<16; jj+=4){
      float4 v = *(const float4*)&ys[r*132 + cg + jj];
      float4 la = *(const float4*)&Lh[base + cg + jj];
      y[jj]   = v.x + 0.1f*la.x; y[jj+1] = v.y + 0.1f*la.y;
      y[jj+2] = v.z + 0.1f*la.z; y[jj+3] = v.w + 0.1f*la.w;
    }
    float s = 0.f, s2 = 0.f;
    #pragma unroll
    for(int jj=0; jj<16; jj++){ s += y[jj]; s2 += y[jj]*y[jj]; }
    #pragma unroll
    for(int m=1; m<8; m<<=1){ s += __shfl_xor(s,m,64); s2 += __shfl_xor(s2,m,64); }
    float mean = s*(1.f/128.f);
    float var  = s2*(1.f/128.f) - mean*mean;
    float rs   = rsqrtf(fmaxf(var, 0.f) + 1e-5f);
    #pragma unroll
    for(int jj=0; jj<16; jj+=4){
      float4 gv = *(const float4*)&lng[cg + jj];
      float4 bv = *(const float4*)&lnb[cg + jj];
      *(float4*)&Lh[base + cg + jj] = make_float4(
        (y[jj]  -mean)*rs*gv.x + bv.x, (y[jj+1]-mean)*rs*gv.y + bv.y,
        (y[jj+2]-mean)*rs*gv.z + bv.z, (y[jj+3]-mean)*rs*gv.w + bv.w);
    }
  }
}

// ---------------------------------------------------------------- heads (MFMA)
__global__ __launch_bounds__(256) void k_head_v2(
    const float* __restrict__ Lh,
    const short* __restrict__ Wdh, const short* __restrict__ Wdl,
    const float* __restrict__ b1d, const float* __restrict__ W2d, const float* __restrict__ b2d,
    const short* __restrict__ Wch, const short* __restrict__ Wcl,
    const float* __restrict__ b1c, const float* __restrict__ W2c, const float* __restrict__ b2c,
    float* __restrict__ out){
  __shared__ short xs[2][32][264];
  __shared__ float ph[2][2][32];
  const int t = threadIdx.x;
  const int lane = t & 63, wv = t >> 6;
  const size_t v0 = (size_t)blockIdx.x * 32;

  {
    #pragma unroll
    for(int r=0; r<8; r++){
      int row = wv*8 + r;
      float4 v = *(const float4*)&Lh[(v0 + row)*256 + lane*4];
      unsigned short hx=f2b(v.x), hy=f2b(v.y), hz=f2b(v.z), hw=f2b(v.w);
      unsigned short lx=f2b(v.x-b2f(hx)), ly=f2b(v.y-b2f(hy));
      unsigned short lz=f2b(v.z-b2f(hz)), lw=f2b(v.w-b2f(hw));
      *(uint2*)&xs[0][row][lane*4] = make_uint2(((unsigned int)hy<<16)|hx, ((unsigned int)hw<<16)|hz);
      *(uint2*)&xs[1][row][lane*4] = make_uint2(((unsigned int)ly<<16)|lx, ((unsigned int)lw<<16)|lz);
    }
  }
  __syncthreads();

  const int hd = wv >> 1, nh = wv & 1;
  const short8* BH = (const short8*)(hd ? Wch : Wdh);
  const short8* BL = (const short8*)(hd ? Wcl : Wdl);
  const float* b1 = hd ? b1c : b1d;
  const float* w2 = hd ? W2c : W2d;
  const int am0 = (lane & 15), am1 = 16 + (lane & 15);
  const int ak = (lane >> 4) * 8;

  float part[2][4] = {{0.f,0.f,0.f,0.f},{0.f,0.f,0.f,0.f}};
  #pragma unroll
  for(int g2=0; g2<2; g2++){
    f32x4 acc[2][4];
    #pragma unroll
    for(int ntl=0; ntl<4; ntl++){
      float bv = b1[(nh*8 + g2*4 + ntl)*16 + (lane & 15)];
      acc[0][ntl] = (f32x4){bv, bv, bv, bv};
      acc[1][ntl] = acc[0][ntl];
    }
    #pragma unroll
    for(int kt=0; kt<8; kt++){
      short8 ah0 = *(const short8*)&xs[0][am0][kt*32 + ak];
      short8 al0 = *(const short8*)&xs[1][am0][kt*32 + ak];
      short8 ah1 = *(const short8*)&xs[0][am1][kt*32 + ak];
      short8 al1 = *(const short8*)&xs[1][am1][kt*32 + ak];
      #pragma unroll
      for(int ntl=0; ntl<4; ntl++){
        int g = nh*8 + g2*4 + ntl;
        short8 bh = BH[(g*8 + kt)*64 + lane];
        short8 bl = BL[(g*8 + kt)*64 + lane];
        acc[0][ntl] = __builtin_amdgcn_mfma_f32_16x16x32_bf16(ah0, bh, acc[0][ntl], 0, 0, 0);
        acc[0][ntl] = __builtin_amdgcn_mfma_f32_16x16x32_bf16(ah0, bl, acc[0][ntl], 0, 0, 0);
        acc[0][ntl] = __builtin_amdgcn_mfma_f32_16x16x32_bf16(al0, bh, acc[0][ntl], 0, 0, 0);
        acc[1][ntl] = __builtin_amdgcn_mfma_f32_16x16x32_bf16(ah1, bh, acc[1][ntl], 0, 0, 0);
        acc[1][ntl] = __builtin_amdgcn_mfma_f32_16x16x32_bf16(ah1, bl, acc[1][ntl], 0, 0, 0);
        acc[1][ntl] = __builtin_amdgcn_mfma_f32_16x16x32_bf16(al1, bh, acc[1][ntl], 0, 0, 0);
      }
    }
    #pragma unroll
    for(int ntl=0; ntl<4; ntl++){
      float wv2 = w2[(nh*8 + g2*4 + ntl)*16 + (lane & 15)];
      #pragma unroll
      for(int rt=0; rt<2; rt++)
        #pragma unroll
        for(int reg=0; reg<4; reg++)
          part[rt][reg] = fmaf(fmaxf(acc[rt][ntl][reg], 0.f), wv2, part[rt][reg]);
    }
  }
  #pragma unroll
  for(int rt=0; rt<2; rt++){
    #pragma unroll
    for(int reg=0; reg<4; reg++){
      float p = part[rt][reg];
      p += __shfl_xor(p, 1, 64);
      p += __shfl_xor(p, 2, 64);
      p += __shfl_xor(p, 4, 64);
      p += __shfl_xor(p, 8, 64);
      if((lane & 15) == 0) ph[hd][nh][rt*16 + (lane >> 4)*4 + reg] = p;
    }
  }
  __syncthreads();
  if(t < 64){
    int h2 = t >> 5, row = t & 31;
    out[(size_t)h2*NVAR + v0 + row] = ph[h2][0][row] + ph[h2][1][row] + (h2 ? b2c[0] : b2d[0]);
  }
}

__global__ __launch_bounds__(256) void k_head_c2(
    const float* __restrict__ C, const float* __restrict__ st,
    const short* __restrict__ Wh, const short* __restrict__ Wl,
    const float* __restrict__ b1, const float* __restrict__ W2, const float* __restrict__ b2,
    float* __restrict__ out){
  __shared__ short xs[2][32][136];
  __shared__ float ph[4][32];
  const int t = threadIdx.x;
  const int lane = t & 63, wv = t >> 6;
  const size_t c0 = (size_t)blockIdx.x * 32;

  {
    const int half = lane >> 5, f4 = (lane & 31) * 4;
    float4 mean4 = *(const float4*)&st[256+f4];
    float4 isd4  = *(const float4*)&st[384+f4];
    const int rb4 = wv*8 + half*4;
    #pragma unroll
    for(int i=0; i<4; i++){
      int row = rb4 + i;
      float4 v = *(const float4*)&C[(c0 + row)*128 + f4];
      v.x = (v.x - mean4.x)*isd4.x; v.y = (v.y - mean4.y)*isd4.y;
      v.z = (v.z - mean4.z)*isd4.z; v.w = (v.w - mean4.w)*isd4.w;
      unsigned short hx=f2b(v.x), hy=f2b(v.y), hz=f2b(v.z), hw=f2b(v.w);
      unsigned short lx=f2b(v.x-b2f(hx)), ly=f2b(v.y-b2f(hy));
      unsigned short lz=f2b(v.z-b2f(hz)), lw=f2b(v.w-b2f(hw));
      *(uint2*)&xs[0][row][f4] = make_uint2(((unsigned int)hy<<16)|hx, ((unsigned int)hw<<16)|hz);
      *(uint2*)&xs[1][row][f4] = make_uint2(((unsigned int)ly<<16)|lx, ((unsigned int)lw<<16)|lz);
    }
  }
  __syncthreads();

  const int am0 = (lane & 15), am1 = 16 + (lane & 15);
  const int ak = (lane >> 4) * 8;
  f32x4 acc[2][2];
  #pragma unroll
  for(int ntl=0; ntl<2; ntl++){
    float bv = b1[(wv*2+ntl)*16 + (lane & 15)];
    acc[0][ntl] = (f32x4){bv, bv, bv, bv};
    acc[1][ntl] = acc[0][ntl];
  }
  const short8* BH = (const short8*)Wh;
  const short8* BL = (const short8*)Wl;
  #pragma unroll
  for(int kt=0; kt<4; kt++){
    short8 ah0 = *(const short8*)&xs[0][am0][kt*32 + ak];
    short8 al0 = *(const short8*)&xs[1][am0][kt*32 + ak];
    short8 ah1 = *(const short8*)&xs[0][am1][kt*32 + ak];
    short8 al1 = *(const short8*)&xs[1][am1][kt*32 + ak];
    #pragma unroll
    for(int ntl=0; ntl<2; ntl++){
      int g = wv*2 + ntl;
      short8 bh = BH[(g*4 + kt)*64 + lane];
      short8 bl = BL[(g*4 + kt)*64 + lane];
      acc[0][ntl] = __builtin_amdgcn_mfma_f32_16x16x32_bf16(ah0, bh, acc[0][ntl], 0, 0, 0);
      acc[0][ntl] = __builtin_amdgcn_mfma_f32_16x16x32_bf16(ah0, bl, acc[0][ntl], 0, 0, 0);
      acc[0][ntl] = __builtin_amdgcn_mfma_f32_16x16x32_bf16(al0, bh, acc[0][ntl], 0, 0, 0);
      acc[1][ntl] = __builtin_amdgcn_mfma_f32_16x16x32_bf16(ah1, bh, acc[1][ntl], 0, 0, 0);
      acc[1][ntl] = __builtin_amdgcn_mfma_f32_16x16x32_bf16(ah1, bl, acc[1][ntl], 0, 0, 0);
      acc[1][ntl] = __builtin_amdgcn_mfma_f32_16x16x32_bf16(al1, bh, acc[1][ntl], 0, 0, 0);
    }
  }
  float part[2][4] = {{0.f,0.f,0.f,0.f},{0.f,0.f,0.f,0.f}};
  #pragma unroll
  for(int ntl=0; ntl<2; ntl++){
    float wv2 = W2[(wv*2+ntl)*16 + (lane & 15)];
    #pragma unroll
    for(int rt=0; rt<2; rt++)
      #pragma unroll
      for(int reg=0; reg<4; reg++)
        part[rt][reg] = fmaf(fmaxf(acc[rt][ntl][reg], 0.f), wv2, part[rt][reg]);
  }
  #pragma unroll
  for(int rt=0; rt<2; rt++){
    #pragma unroll
    for(int reg=0; reg<4; reg++){
      float p = part[rt][reg];
      p += __shfl_xor(p, 1, 64);
      p += __shfl_xor(p, 2, 64);
      p += __shfl_xor(p, 4, 64);
      p += __shfl_xor(p, 8, 64);
      if((lane & 15) == 0) ph[wv][rt*16 + (lane >> 4)*4 + reg] = p;
    }
  }
  __syncthreads();
  if(t < 32) out[c0 + t] = ((ph[0][t] + ph[1][t]) + ph[2][t]) + ph[3][t] + b2[0];
}

// ---------------------------------------------------------------- launch
extern "C" void kernel_launch(void* const* d_in, const int* in_sizes, int n_in,
                              void* d_out, int out_size, void* d_ws, size_t ws_size,
                              hipStream_t stream){
  const float* L0   = (const float*)d_in[0];
  const float* lng  = (const float*)d_in[1];
  const float* lnb  = (const float*)d_in[2];
  const float* CuW1 = (const float*)d_in[3];
  const float* Cub1 = (const float*)d_in[4];
  const float* CuW2 = (const float*)d_in[5];
  const float* Cub2 = (const float*)d_in[6];
  const float* LuW1 = (const float*)d_in[7];
  const float* Lub1 = (const float*)d_in[8];
  const float* LuW2 = (const float*)d_in[9];
  const float* Lub2 = (const float*)d_in[10];
  const float* VdW1 = (const float*)d_in[11];
  const float* Vdb1 = (const float*)d_in[12];
  const float* VdW2 = (const float*)d_in[13];
  const float* Vdb2 = (const float*)d_in[14];
  const float* VcW1 = (const float*)d_in[15];
  const float* Vcb1 = (const float*)d_in[16];
  const float* VcW2 = (const float*)d_in[17];
  const float* Vcb2 = (const float*)d_in[18];
  const float* CsW1 = (const float*)d_in[19];
  const float* Csb1 = (const float*)d_in[20];
  const float* CsW2 = (const float*)d_in[21];
  const float* Csb2 = (const float*)d_in[22];
  const int* cidx = (const int*)d_in[23];
  const int* lidx = (const int*)d_in[24];
  const int  ne   = in_sizes[23];

  float* ws   = (float*)d_ws;
  float* Lh   = ws;                        // 25,600,000 f32 (Lvar paired layout)
  float* C    = ws + 25600000;             // 38,400,000 f32 -> end 64,000,000
  float* st   = ws + 64000000;             // 512: mean|isd at +256/+384
  short* W1h  = (short*)(ws + 64000512);   // 65,536 bf16
  short* W1l  = (short*)(ws + 64033280);   // 65,536 bf16
  short* W2h  = (short*)(ws + 64066048);   // 32,768 bf16
  short* W2l  = (short*)(ws + 64082432);   // 32,768 bf16
  short* W3h  = (short*)(ws + 64098816);   // 16,384 bf16 (LuW1 hi)
  short* W3l  = (short*)(ws + 64107008);   // 16,384 bf16
  short* W4h  = (short*)(ws + 64115200);   // 16,384 bf16 (LuW2 hi)
  short* W4l  = (short*)(ws + 64123392);   // 16,384 bf16
  int*   ib   = (int*)(ws + 64131584);     // int region
  int*   Pc   = ib;                        // PAD_C = 300,032
  int*   Pl   = ib + PAD_C;                // PAD_L = 200,704
  int*   clit = ib + PAD_C + PAD_L;        // 1,000,000 (packed Lvar offsets)
  int*   lcl  = clit + 1000000;            // 1,000,000 (packed C offsets)
  int*   psum = lcl + 1000000;             // 512
  float* part = ws + 66632832;             // 2*1563*128 = 400,128 -> 67,032,960
  // Head weights packed AFTER hop loop, overlaying then-dead part region:
  short* W5h  = (short*)(ws + 66632832);   // VdW1 hi (32,768 fl)
  short* W5l  = (short*)(ws + 66665600);
  short* W6h  = (short*)(ws + 66698368);   // VcW1
  short* W6l  = (short*)(ws + 66731136);
  short* W7h  = (short*)(ws + 66763904);   // CsW1 (8,192 fl)
  short* W7l  = (short*)(ws + 66772096);   // ends 66,780,288
  float* out = (float*)d_out;              // fp32: drat|core|c_core

  k_init_lh4<<<25000, 256, 0, stream>>>((const float4*)L0, (float4*)Lh);
  k_pack_w<<<256, 256, 0, stream>>>(CuW1, W1h, W1l, 256, 256);
  k_pack_w<<<128, 256, 0, stream>>>(CuW2, W2h, W2l, 256, 128);
  k_pack_w<<<64, 256, 0, stream>>>(LuW1, W3h, W3l, 128, 128);
  k_pack_w<<<64, 256, 0, stream>>>(LuW2, W4h, W4l, 128, 128);

  // CSR build (counting sort both directions) + canonical intra-row order
  k_zero4<<<489, 256, 0, stream>>>((float4*)Pc, (PAD_C + PAD_L)/4);
  k_hist<<<(ne+255)/256, 256, 0, stream>>>(cidx, lidx, Pc, Pl, ne);
  k_scan_pass1<<<NB_C, 256, 0, stream>>>(Pc, psum);
  k_scan_pass2<<<1, 512, 0, stream>>>(psum, NB_C);
  k_scan_pass3<<<NB_C, 256, 0, stream>>>(Pc, psum);
  k_scan_pass1<<<NB_L, 256, 0, stream>>>(Pl, psum);
  k_scan_pass2<<<1, 512, 0, stream>>>(psum, NB_L);
  k_scan_pass3<<<NB_L, 256, 0, stream>>>(Pl, psum);
  k_fill<<<(ne+255)/256, 256, 0, stream>>>(cidx, lidx, Pc, Pl, clit, lcl, ne);
  k_sortmap<<<(NCL+255)/256, 256, 0, stream>>>(Pc, clit, lidx, NCL, 0);
  k_sortmap<<<(NLIT+255)/256, 256, 0, stream>>>(Pl, lcl, cidx, NLIT, 1);

  for(int hop=0; hop<4; hop++){
    k_clause_fused<<<CGRID, 512, 0, stream>>>(Pc, clit, Lh,
        W1h, W1l, Cub1, W2h, W2l, Cub2, C, part);
    k_finstats<<<1, 512, 0, stream>>>(part, st);
    k_lit_fused<<<6250, 256, 0, stream>>>(Pl, lcl, C, st, W3h, W3l, Lub1,
        W4h, W4l, Lub2, lng, lnb, Lh);
  }

  // head weights packed AFTER hops, overlaying dead part region
  k_pack_w<<<256, 256, 0, stream>>>(VdW1, W5h, W5l, 256, 256);
  k_pack_w<<<256, 256, 0, stream>>>(VcW1, W6h, W6l, 256, 256);
  k_pack_w<<<64, 256, 0, stream>>>(CsW1, W7h, W7l, 128, 128);
  k_head_v2<<<3125, 256, 0, stream>>>(Lh, W5h, W5l, Vdb1, VdW2, Vdb2, W6h, W6l, Vcb1, VcW2, Vcb2, out);
  k_head_c2<<<9375, 256, 0, stream>>>(C, st, W7h, W7l, Csb1, CsW2, Csb2, out + 200000);
}

// Round 16
// 2397.490 us; speedup vs baseline: 2.0323x; 2.0323x over previous
//
#include <hip/hip_runtime.h>
#include <hip/hip_bf16.h>

#define NCL   300000
#define NLIT  200000
#define HALFL 100000
#define NVAR  100000

#define NB_C  293            // 293*1024 = 300032 >= NCL
#define PAD_C (NB_C*1024)
#define NB_L  196            // 196*1024 = 200704 >= NLIT
#define PAD_L (NB_L*1024)

typedef __attribute__((ext_vector_type(8))) short short8;   // 8 bf16 (4 VGPRs)
typedef __attribute__((ext_vector_type(4))) float f32x4;    // MFMA acc

__device__ __forceinline__ unsigned short f2b(float x){     // fp32 -> bf16 RNE
  union{float f; unsigned int u;} v; v.f = x;
  unsigned int r = v.u + 0x7FFF + ((v.u >> 16) & 1);
  return (unsigned short)(r >> 16);
}
__device__ __forceinline__ float b2f(unsigned short u){
  union{unsigned int i; float f;} x; x.i = ((unsigned int)u) << 16; return x.f;
}
__device__ __forceinline__ int imax(int a, int b){ return a > b ? a : b; }

// Lh uses PAIRED layout: Lvar[v][0..127] = lit v, Lvar[v][128..255] = lit v+HALFL.

// ---------------------------------------------------------------- utilities
__global__ void k_init_lh4(const float4* __restrict__ L04, float4* __restrict__ Lh4){
  int i = blockIdx.x*256 + threadIdx.x;            // 6,400,000 float4
  Lh4[i] = L04[i & 31];                            // (4i)&127 == 4*(i&31): exact
}

__global__ void k_zero4(float4* __restrict__ p, int n4){
  int i = blockIdx.x*256 + threadIdx.x;
  if(i < n4) p[i] = make_float4(0.f,0.f,0.f,0.f);
}

// Pack fp32 row-major W[K][N] into hi/lo bf16 MFMA B-fragment order
__global__ void k_pack_w(const float* __restrict__ W, short* __restrict__ Whi,
                         short* __restrict__ Wlo, int K, int N){
  int i = blockIdx.x*256 + threadIdx.x;
  if(i >= K*N) return;
  int j  = i & 7;
  int L  = (i >> 3) & 63;
  int kt = (i >> 9) % (K >> 5);
  int nt = (i >> 9) / (K >> 5);
  int k = kt*32 + ((L >> 4) << 3) + j;
  int n = nt*16 + (L & 15);
  float w = W[(size_t)k*N + n];
  unsigned short hi = f2b(w);
  Whi[i] = (short)hi;
  Wlo[i] = (short)f2b(w - b2f(hi));
}

// ---------------------------------------------------------------- CSR build
__global__ __launch_bounds__(256) void k_hist(const int* __restrict__ ci, const int* __restrict__ li,
    int* __restrict__ Pc, int* __restrict__ Pl, int ne){
  int e = blockIdx.x*256 + threadIdx.x;
  if(e < ne){ atomicAdd(&Pc[ci[e]], 1); atomicAdd(&Pl[li[e]], 1); }
}

__global__ __launch_bounds__(256) void k_scan_pass1(const int* __restrict__ P, int* __restrict__ psum){
  __shared__ int red[256];
  int t = threadIdx.x;
  int4 v = *(const int4*)&P[blockIdx.x*1024 + t*4];
  red[t] = v.x + v.y + v.z + v.w;
  __syncthreads();
  for(int ofs=128; ofs>0; ofs>>=1){
    if(t < ofs) red[t] += red[t+ofs];
    __syncthreads();
  }
  if(t == 0) psum[blockIdx.x] = red[0];
}

__global__ __launch_bounds__(512) void k_scan_pass2(int* __restrict__ psum, int nb){
  __shared__ int sA[512], sB[512];
  int t = threadIdx.x;
  sA[t] = (t < nb) ? psum[t] : 0;
  __syncthreads();
  int* src = sA; int* dst = sB;
  for(int ofs=1; ofs<512; ofs<<=1){
    int x = src[t];
    if(t >= ofs) x += src[t-ofs];
    dst[t] = x;
    __syncthreads();
    int* tmp = src; src = dst; dst = tmp;
  }
  psum[t] = t ? src[t-1] : 0;    // exclusive
}

__global__ __launch_bounds__(256) void k_scan_pass3(int* __restrict__ P, const int* __restrict__ psum){
  __shared__ int sA[256], sB[256];
  int t = threadIdx.x;
  int base = blockIdx.x*1024 + t*4;
  int4 v = *(const int4*)&P[base];
  int tsum = v.x + v.y + v.z + v.w;
  sA[t] = tsum;
  __syncthreads();
  int* src = sA; int* dst = sB;
  for(int ofs=1; ofs<256; ofs<<=1){
    int x = src[t];
    if(t >= ofs) x += src[t-ofs];
    dst[t] = x;
    __syncthreads();
    int* tmp = src; src = dst; dst = tmp;
  }
  int excl = psum[blockIdx.x] + src[t] - tsum;
  int4 o;
  o.x = excl;
  o.y = o.x + v.x;
  o.z = o.y + v.y;
  o.w = o.z + v.z;
  *(int4*)&P[base] = o;
}

// After k_fill, P[c] holds END offset of row c; begin(c) = c ? P[c-1] : 0.
__global__ __launch_bounds__(256) void k_fill(const int* __restrict__ ci, const int* __restrict__ li,
    int* __restrict__ Pc, int* __restrict__ Pl, int* __restrict__ clit, int* __restrict__ lcl, int ne){
  int e = blockIdx.x*256 + threadIdx.x;
  if(e < ne){
    int c = ci[e], l = li[e];
    clit[atomicAdd(&Pc[c], 1)] = e;
    lcl [atomicAdd(&Pl[l], 1)] = e;
  }
}

// Canonicalize each row slice: sort edge ids ascending, then map to PACKED offsets.
// mode 0 (clause side): lit l -> Lvar offset (v<<8 | s*128)
// mode 1 (lit side):    clause c -> C row offset (c<<7)
__global__ __launch_bounds__(256) void k_sortmap(const int* __restrict__ P,
    int* __restrict__ slots, const int* __restrict__ map, int nrows, int mode){
  int r = blockIdx.x*256 + threadIdx.x;
  if(r >= nrows) return;
  int b = r ? P[r-1] : 0;
  int e = P[r];
  for(int i=b; i<e-1; i++){
    int mi = i, mv = slots[i];
    for(int j=i+1; j<e; j++){ int v = slots[j]; if(v < mv){ mv = v; mi = j; } }
    slots[mi] = slots[i]; slots[i] = mv;
  }
  for(int i=b; i<e; i++){
    int l = map[slots[i]];
    slots[i] = mode ? (l << 7)
                    : ((l < HALFL) ? (l << 8) : (((l - HALFL) << 8) | 128));
  }
}

// ------ clause side: CSR gather + COMPENSATED bf16 MFMA MLP 256->256->128
// 512 thr, 64 clauses/block, grid 4688 (champion config — ONE tile per block).
__global__ __launch_bounds__(512, 4) void k_clause_fused(
    const int* __restrict__ Pc, const int* __restrict__ clit,
    const float* __restrict__ Lh,
    const short* __restrict__ W1h, const short* __restrict__ W1l, const float* __restrict__ b1,
    const short* __restrict__ W2h, const short* __restrict__ W2l, const float* __restrict__ b2,
    float* __restrict__ Y){
  __shared__ short xs[2][64][264];
  __shared__ int rng[65];
  const int t = threadIdx.x;
  const int r0 = blockIdx.x * 64;

  if(t < 65) rng[t] = (r0 + t == 0) ? 0 : Pc[r0 + t - 1];
  __syncthreads();

  const int lane = t & 63, wv = t >> 6;
  { // gather: lanes 0-31 direct half, 32-63 flipped; 1 contiguous KB per row
    const int hxor = (lane >> 5) << 7;       // 0 / 128: selects Lvar half
    const int f4 = (lane & 31) * 4;
    const int rb = wv*8;
    int eb[8], dd[8];
    #pragma unroll
    for(int i=0;i<8;i++){ eb[i]=rng[rb+i]; dd[i]=rng[rb+i+1]-eb[i]; }
    int md = 0;
    #pragma unroll
    for(int i=0;i<8;i++) md = imax(md, dd[i]);
    float4 a[8];
    int li[8];
    #pragma unroll
    for(int i=0;i<8;i++){ a[i]=make_float4(0.f,0.f,0.f,0.f); li[i]=(dd[i]>0)?clit[eb[i]]:0; }
    for(int s=0; s<md; s++){
      float4 v[8];
      #pragma unroll
      for(int i=0;i<8;i++) v[i] = *(const float4*)&Lh[(size_t)((li[i] ^ hxor) + f4)];
      int p[8];
      #pragma unroll
      for(int i=0;i<8;i++) p[i] = (s+1<dd[i]) ? clit[eb[i]+s+1] : 0;
      #pragma unroll
      for(int i=0;i<8;i++){
        float m = (s<dd[i]) ? 1.f : 0.f;
        a[i].x=fmaf(m,v[i].x,a[i].x); a[i].y=fmaf(m,v[i].y,a[i].y);
        a[i].z=fmaf(m,v[i].z,a[i].z); a[i].w=fmaf(m,v[i].w,a[i].w);
        li[i]=p[i];
      }
    }
    #pragma unroll
    for(int i=0;i<8;i++){
      float4 aa = a[i];
      unsigned short hx=f2b(aa.x), hy=f2b(aa.y), hz=f2b(aa.z), hw=f2b(aa.w);
      unsigned short lx=f2b(aa.x-b2f(hx)), ly=f2b(aa.y-b2f(hy));
      unsigned short lz=f2b(aa.z-b2f(hz)), lw=f2b(aa.w-b2f(hw));
      *(uint2*)&xs[0][rb+i][hxor + f4] =
        make_uint2(((unsigned int)hy<<16)|hx, ((unsigned int)hw<<16)|hz);
      *(uint2*)&xs[1][rb+i][hxor + f4] =
        make_uint2(((unsigned int)ly<<16)|lx, ((unsigned int)lw<<16)|lz);
    }
  }
  __syncthreads();

  const int c16 = lane & 15;
  const int ak  = (lane >> 4) * 8;

  // layer 1: 256 -> 256; wave owns nt = wv*2+ntl for ALL 4 row tiles
  f32x4 acc[4][2];
  #pragma unroll
  for(int ntl=0; ntl<2; ntl++){
    float bv = b1[(wv*2+ntl)*16 + c16];
    #pragma unroll
    for(int rt=0; rt<4; rt++) acc[rt][ntl] = (f32x4){bv, bv, bv, bv};
  }
  {
    const short8* Bh = (const short8*)W1h;
    const short8* Bl = (const short8*)W1l;
    #pragma unroll
    for(int kt=0; kt<8; kt++){
      short8 ah[4], al[4];
      #pragma unroll
      for(int rt=0; rt<4; rt++){
        ah[rt] = *(const short8*)&xs[0][rt*16 + c16][kt*32 + ak];
        al[rt] = *(const short8*)&xs[1][rt*16 + c16][kt*32 + ak];
      }
      #pragma unroll
      for(int ntl=0; ntl<2; ntl++){
        int g = wv*2 + ntl;
        short8 bh = Bh[(g*8 + kt)*64 + lane];
        short8 bl = Bl[(g*8 + kt)*64 + lane];
        #pragma unroll
        for(int rt=0; rt<4; rt++){
          acc[rt][ntl] = __builtin_amdgcn_mfma_f32_16x16x32_bf16(ah[rt], bh, acc[rt][ntl], 0, 0, 0);
          acc[rt][ntl] = __builtin_amdgcn_mfma_f32_16x16x32_bf16(ah[rt], bl, acc[rt][ntl], 0, 0, 0);
          acc[rt][ntl] = __builtin_amdgcn_mfma_f32_16x16x32_bf16(al[rt], bh, acc[rt][ntl], 0, 0, 0);
        }
      }
    }
  }
  __syncthreads();
  #pragma unroll
  for(int rt=0; rt<4; rt++){
    #pragma unroll
    for(int ntl=0; ntl<2; ntl++){
      int col = (wv*2 + ntl)*16 + c16;
      int rowb = rt*16 + ((lane >> 4) << 2);
      #pragma unroll
      for(int reg=0; reg<4; reg++){
        float v = fmaxf(acc[rt][ntl][reg], 0.f);
        unsigned short hi = f2b(v);
        xs[0][rowb + reg][col] = (short)hi;
        xs[1][rowb + reg][col] = (short)f2b(v - b2f(hi));
      }
    }
  }
  __syncthreads();

  // layer 2: 256 -> 128; wave owns nt = wv for ALL 4 row tiles
  f32x4 o4[4];
  {
    float bv = b2[wv*16 + c16];
    #pragma unroll
    for(int rt=0; rt<4; rt++) o4[rt] = (f32x4){bv, bv, bv, bv};
  }
  {
    const short8* Bh = (const short8*)W2h;
    const short8* Bl = (const short8*)W2l;
    #pragma unroll
    for(int kt=0; kt<8; kt++){
      short8 ah[4], al[4];
      #pragma unroll
      for(int rt=0; rt<4; rt++){
        ah[rt] = *(const short8*)&xs[0][rt*16 + c16][kt*32 + ak];
        al[rt] = *(const short8*)&xs[1][rt*16 + c16][kt*32 + ak];
      }
      short8 bh = Bh[(wv*8 + kt)*64 + lane];
      short8 bl = Bl[(wv*8 + kt)*64 + lane];
      #pragma unroll
      for(int rt=0; rt<4; rt++){
        o4[rt] = __builtin_amdgcn_mfma_f32_16x16x32_bf16(ah[rt], bh, o4[rt], 0, 0, 0);
        o4[rt] = __builtin_amdgcn_mfma_f32_16x16x32_bf16(ah[rt], bl, o4[rt], 0, 0, 0);
        o4[rt] = __builtin_amdgcn_mfma_f32_16x16x32_bf16(al[rt], bh, o4[rt], 0, 0, 0);
      }
    }
  }
  #pragma unroll
  for(int rt=0; rt<4; rt++){
    int col = wv*16 + c16;
    int rowb = r0 + rt*16 + ((lane >> 4) << 2);
    #pragma unroll
    for(int reg=0; reg<4; reg++){
      int rr = rowb + reg;
      if(rr < NCL) Y[(size_t)rr*128 + col] = o4[rt][reg];   // tail rows skipped
    }
  }
}

// ---------------------------------------------------------------- col stats
// DETERMINISTIC + COALESCED: block b reads a CONTIGUOUS band of 586 rows as
// float4 (sequential 300 KB -> full HBM BW). Fixed per-thread row stride +
// fixed LDS tree; block-exclusive part slot.
__global__ __launch_bounds__(256) void k_colstats2(const float* __restrict__ C, float* __restrict__ part){
  const int t = threadIdx.x;
  const int c4 = t & 31;          // float4 column 0..31
  const int rsub = t >> 5;        // 0..7
  const int rbeg = blockIdx.x * 586;             // 512*586 = 300,032 >= NCL
  int rend = rbeg + 586; if(rend > NCL) rend = NCL;
  float4 s = make_float4(0.f,0.f,0.f,0.f), q = s;
  for(int r = rbeg + rsub; r < rend; r += 8){
    float4 v = *(const float4*)&C[(size_t)r*128 + c4*4];
    s.x += v.x; s.y += v.y; s.z += v.z; s.w += v.w;
    q.x = fmaf(v.x,v.x,q.x); q.y = fmaf(v.y,v.y,q.y);
    q.z = fmaf(v.z,v.z,q.z); q.w = fmaf(v.w,v.w,q.w);
  }
  __shared__ float4 red[256];
  red[t] = s; __syncthreads();
  if(rsub < 4){ float4 o = red[t+128]; red[t].x+=o.x; red[t].y+=o.y; red[t].z+=o.z; red[t].w+=o.w; }
  __syncthreads();
  if(rsub < 2){ float4 o = red[t+64];  red[t].x+=o.x; red[t].y+=o.y; red[t].z+=o.z; red[t].w+=o.w; }
  __syncthreads();
  if(rsub < 1){
    float4 o = red[t+32];
    float4 r4 = make_float4(red[t].x+o.x, red[t].y+o.y, red[t].z+o.z, red[t].w+o.w);
    *(float4*)&part[blockIdx.x*128 + c4*4] = r4;
  }
  __syncthreads();
  red[t] = q; __syncthreads();
  if(rsub < 4){ float4 o = red[t+128]; red[t].x+=o.x; red[t].y+=o.y; red[t].z+=o.z; red[t].w+=o.w; }
  __syncthreads();
  if(rsub < 2){ float4 o = red[t+64];  red[t].x+=o.x; red[t].y+=o.y; red[t].z+=o.z; red[t].w+=o.w; }
  __syncthreads();
  if(rsub < 1){
    float4 o = red[t+32];
    float4 r4 = make_float4(red[t].x+o.x, red[t].y+o.y, red[t].z+o.z, red[t].w+o.w);
    *(float4*)&part[65536 + blockIdx.x*128 + c4*4] = r4;
  }
}

// Reduce 512 partials per column in fixed strided order -> mean, 1/(std+eps).
__global__ __launch_bounds__(512) void k_finstats(const float* __restrict__ part, float* __restrict__ st){
  __shared__ float red[2][512];
  const int t = threadIdx.x, j = t & 127, h = t >> 7;   // h in 0..3
  float s = 0.f, s2 = 0.f;
  for(int b = h; b < 512; b += 4){
    s  += part[b*128 + j];
    s2 += part[65536 + b*128 + j];
  }
  red[0][t] = s; red[1][t] = s2; __syncthreads();
  if(t < 128){
    float S  = red[0][j] + red[0][j+128] + red[0][j+256] + red[0][j+384];
    float S2 = red[1][j] + red[1][j+128] + red[1][j+256] + red[1][j+384];
    const float n = (float)NCL;
    float mean = S/n;
    float var = (S2 - n*mean*mean) / (n - 1.f);   // ddof=1
    var = fmaxf(var, 0.f);
    st[256+j] = mean;
    st[384+j] = 1.f/(sqrtf(var) + 1e-10f);
  }
}

// -- literal side: gather(normalized) + COMPENSATED bf16 MFMA 128->128->128
//    + 0.1*residual + LayerNorm. 256 thr, 32 lits/block. (champion verbatim)
__global__ __launch_bounds__(256) void k_lit_fused(
    const int* __restrict__ Pl, const int* __restrict__ lcl,
    const float* __restrict__ C, const float* __restrict__ st,
    const short* __restrict__ W1h, const short* __restrict__ W1l, const float* __restrict__ b1,
    const short* __restrict__ W2h, const short* __restrict__ W2l, const float* __restrict__ b2,
    const float* __restrict__ lng, const float* __restrict__ lnb, float* __restrict__ Lh){
  __shared__ short xs[2][32][136];
  __shared__ int rng[33];
  float* ys = (float*)&xs[0][0][0];          // [32][132] fp32, aliases xs
  const int t = threadIdx.x;
  const int r0 = blockIdx.x * 32;
  const int sflag = (r0 >= HALFL) ? 1 : 0;               // Lvar half
  const size_t vb = (size_t)(r0 - (sflag ? HALFL : 0));  // Lvar base row

  if(t < 33) rng[t] = (r0 + t == 0) ? 0 : Pl[r0 + t - 1];
  __syncthreads();

  const int lane = t & 63, wv = t >> 6;
  { // gather: half-wave rows wv*8+half*4 .. +3, interleaved; f4/lane covers 128
    const int half = lane >> 5, f4 = (lane & 31) * 4;
    float4 mean4 = *(const float4*)&st[256+f4];
    float4 isd4  = *(const float4*)&st[384+f4];
    const int rb4 = wv*8 + half*4;
    const int e0=rng[rb4+0], d0=rng[rb4+1]-e0;
    const int e1=rng[rb4+1], d1=rng[rb4+2]-e1;
    const int e2=rng[rb4+2], d2=rng[rb4+3]-e2;
    const int e3=rng[rb4+3], d3=rng[rb4+4]-e3;
    float4 a0=make_float4(0.f,0.f,0.f,0.f), a1=a0, a2=a0, a3=a0;
    int l0=(d0>0)?lcl[e0]:0, l1=(d1>0)?lcl[e1]:0;
    int l2=(d2>0)?lcl[e2]:0, l3=(d3>0)?lcl[e3]:0;
    const int md = imax(imax(d0,d1), imax(d2,d3));
    for(int s=0; s<md; s++){
      float4 v0 = *(const float4*)&C[(size_t)l0 + f4];   // lcl pre-scaled c<<7
      float4 v1 = *(const float4*)&C[(size_t)l1 + f4];
      float4 v2 = *(const float4*)&C[(size_t)l2 + f4];
      float4 v3 = *(const float4*)&C[(size_t)l3 + f4];
      int p0=(s+1<d0)?lcl[e0+s+1]:0;
      int p1=(s+1<d1)?lcl[e1+s+1]:0;
      int p2=(s+1<d2)?lcl[e2+s+1]:0;
      int p3=(s+1<d3)?lcl[e3+s+1]:0;
      float m0=(s<d0)?1.f:0.f, m1=(s<d1)?1.f:0.f;
      float m2=(s<d2)?1.f:0.f, m3=(s<d3)?1.f:0.f;
      a0.x=fmaf(m0,v0.x,a0.x); a0.y=fmaf(m0,v0.y,a0.y); a0.z=fmaf(m0,v0.z,a0.z); a0.w=fmaf(m0,v0.w,a0.w);
      a1.x=fmaf(m1,v1.x,a1.x); a1.y=fmaf(m1,v1.y,a1.y); a1.z=fmaf(m1,v1.z,a1.z); a1.w=fmaf(m1,v1.w,a1.w);
      a2.x=fmaf(m2,v2.x,a2.x); a2.y=fmaf(m2,v2.y,a2.y); a2.z=fmaf(m2,v2.z,a2.z); a2.w=fmaf(m2,v2.w,a2.w);
      a3.x=fmaf(m3,v3.x,a3.x); a3.y=fmaf(m3,v3.y,a3.y); a3.z=fmaf(m3,v3.z,a3.z); a3.w=fmaf(m3,v3.w,a3.w);
      l0=p0; l1=p1; l2=p2; l3=p3;
    }
    float4 aa[4] = {a0, a1, a2, a3};
    float dd[4] = {(float)d0, (float)d1, (float)d2, (float)d3};
    #pragma unroll
    for(int i=0;i<4;i++){
      float4 a = aa[i];
      float dg = dd[i];
      a.x = (a.x - dg*mean4.x)*isd4.x; a.y = (a.y - dg*mean4.y)*isd4.y;
      a.z = (a.z - dg*mean4.z)*isd4.z; a.w = (a.w - dg*mean4.w)*isd4.w;
      unsigned short hx=f2b(a.x), hy=f2b(a.y), hz=f2b(a.z), hw=f2b(a.w);
      unsigned short lx=f2b(a.x-b2f(hx)), ly=f2b(a.y-b2f(hy));
      unsigned short lz=f2b(a.z-b2f(hz)), lw=f2b(a.w-b2f(hw));
      *(uint2*)&xs[0][rb4+i][f4] = make_uint2(((unsigned int)hy<<16)|hx, ((unsigned int)hw<<16)|hz);
      *(uint2*)&xs[1][rb4+i][f4] = make_uint2(((unsigned int)ly<<16)|lx, ((unsigned int)lw<<16)|lz);
    }
  }
  __syncthreads();

  const int c16 = lane & 15;
  const int ak  = (lane >> 4) * 8;
  const int am0 = c16, am1 = 16 + c16;

  // layer 1: 128 -> 128; wave owns nt = wv*2+ntl for BOTH row tiles
  f32x4 acc[2][2];                        // [rt][ntl]
  #pragma unroll
  for(int ntl=0; ntl<2; ntl++){
    float bv = b1[(wv*2+ntl)*16 + c16];
    acc[0][ntl] = (f32x4){bv, bv, bv, bv};
    acc[1][ntl] = acc[0][ntl];
  }
  {
    const short8* Bh = (const short8*)W1h;
    const short8* Bl = (const short8*)W1l;
    #pragma unroll
    for(int kt=0; kt<4; kt++){
      short8 ah0 = *(const short8*)&xs[0][am0][kt*32 + ak];
      short8 al0 = *(const short8*)&xs[1][am0][kt*32 + ak];
      short8 ah1 = *(const short8*)&xs[0][am1][kt*32 + ak];
      short8 al1 = *(const short8*)&xs[1][am1][kt*32 + ak];
      #pragma unroll
      for(int ntl=0; ntl<2; ntl++){
        int g = wv*2 + ntl;
        short8 bh = Bh[(g*4 + kt)*64 + lane];
        short8 bl = Bl[(g*4 + kt)*64 + lane];
        acc[0][ntl] = __builtin_amdgcn_mfma_f32_16x16x32_bf16(ah0, bh, acc[0][ntl], 0, 0, 0);
        acc[0][ntl] = __builtin_amdgcn_mfma_f32_16x16x32_bf16(ah0, bl, acc[0][ntl], 0, 0, 0);
        acc[0][ntl] = __builtin_amdgcn_mfma_f32_16x16x32_bf16(al0, bh, acc[0][ntl], 0, 0, 0);
        acc[1][ntl] = __builtin_amdgcn_mfma_f32_16x16x32_bf16(ah1, bh, acc[1][ntl], 0, 0, 0);
        acc[1][ntl] = __builtin_amdgcn_mfma_f32_16x16x32_bf16(ah1, bl, acc[1][ntl], 0, 0, 0);
        acc[1][ntl] = __builtin_amdgcn_mfma_f32_16x16x32_bf16(al1, bh, acc[1][ntl], 0, 0, 0);
      }
    }
  }
  __syncthreads();
  // hidden: ReLU -> hi/lo bf16, overwrite xs
  #pragma unroll
  for(int rt=0; rt<2; rt++){
    #pragma unroll
    for(int ntl=0; ntl<2; ntl++){
      int col = (wv*2 + ntl)*16 + c16;
      int rowb = rt*16 + ((lane >> 4) << 2);
      #pragma unroll
      for(int reg=0; reg<4; reg++){
        float v = fmaxf(acc[rt][ntl][reg], 0.f);
        unsigned short hi = f2b(v);
        xs[0][rowb + reg][col] = (short)hi;
        xs[1][rowb + reg][col] = (short)f2b(v - b2f(hi));
      }
    }
  }
  __syncthreads();

  // layer 2: 128 -> 128 (A-frags loaded upfront, then xs is reused as ys)
  const int rt  = wv & 1;
  const int ntb = (wv >> 1) * 4;
  const int am  = rt*16 + c16;
  short8 a2h[4], a2l[4];
  #pragma unroll
  for(int kt=0; kt<4; kt++){
    a2h[kt] = *(const short8*)&xs[0][am][kt*32 + ak];
    a2l[kt] = *(const short8*)&xs[1][am][kt*32 + ak];
  }
  __syncthreads();                         // all xs reads done -> ys writable
  f32x4 o4[4];
  #pragma unroll
  for(int ntl=0; ntl<4; ntl++){
    float bv = b2[(ntb+ntl)*16 + c16];
    o4[ntl] = (f32x4){bv, bv, bv, bv};
  }
  {
    const short8* Bh = (const short8*)W2h;
    const short8* Bl = (const short8*)W2l;
    #pragma unroll
    for(int kt=0; kt<4; kt++){
      #pragma unroll
      for(int ntl=0; ntl<4; ntl++){
        int g = ntb + ntl;
        short8 bh = Bh[(g*4 + kt)*64 + lane];
        short8 bl = Bl[(g*4 + kt)*64 + lane];
        o4[ntl] = __builtin_amdgcn_mfma_f32_16x16x32_bf16(a2h[kt], bh, o4[ntl], 0, 0, 0);
        o4[ntl] = __builtin_amdgcn_mfma_f32_16x16x32_bf16(a2h[kt], bl, o4[ntl], 0, 0, 0);
        o4[ntl] = __builtin_amdgcn_mfma_f32_16x16x32_bf16(a2l[kt], bh, o4[ntl], 0, 0, 0);
      }
    }
  }
  #pragma unroll
  for(int ntl=0; ntl<4; ntl++){
    int col = (ntb + ntl)*16 + c16;
    int rowb = rt*16 + ((lane >> 4) << 2);
    #pragma unroll
    for(int reg=0; reg<4; reg++)
      ys[(rowb + reg)*132 + col] = o4[ntl][reg];
  }
  __syncthreads();

  { // residual + LayerNorm: 8 threads per row, 16 cols each; Lvar addressing
    const int r  = t >> 3;                 // 0..31
    const int cg = (t & 7) * 16;
    const size_t base = (vb + r)*256 + sflag*128;
    float y[16];
    #pragma unroll
    for(int jj=0; jj<16; jj+=4){
      float4 v = *(const float4*)&ys[r*132 + cg + jj];
      float4 la = *(const float4*)&Lh[base + cg + jj];
      y[jj]   = v.x + 0.1f*la.x; y[jj+1] = v.y + 0.1f*la.y;
      y[jj+2] = v.z + 0.1f*la.z; y[jj+3] = v.w + 0.1f*la.w;
    }
    float s = 0.f, s2 = 0.f;
    #pragma unroll
    for(int jj=0; jj<16; jj++){ s += y[jj]; s2 += y[jj]*y[jj]; }
    #pragma unroll
    for(int m=1; m<8; m<<=1){ s += __shfl_xor(s,m,64); s2 += __shfl_xor(s2,m,64); }
    float mean = s*(1.f/128.f);
    float var  = s2*(1.f/128.f) - mean*mean;
    float rs   = rsqrtf(fmaxf(var, 0.f) + 1e-5f);
    #pragma unroll
    for(int jj=0; jj<16; jj+=4){
      float4 gv = *(const float4*)&lng[cg + jj];
      float4 bv = *(const float4*)&lnb[cg + jj];
      *(float4*)&Lh[base + cg + jj] = make_float4(
        (y[jj]  -mean)*rs*gv.x + bv.x, (y[jj+1]-mean)*rs*gv.y + bv.y,
        (y[jj+2]-mean)*rs*gv.z + bv.z, (y[jj+3]-mean)*rs*gv.w + bv.w);
    }
  }
}

// ---------------------------------------------------------------- heads (MFMA)
__global__ __launch_bounds__(256) void k_head_v2(
    const float* __restrict__ Lh,
    const short* __restrict__ Wdh, const short* __restrict__ Wdl,
    const float* __restrict__ b1d, const float* __restrict__ W2d, const float* __restrict__ b2d,
    const short* __restrict__ Wch, const short* __restrict__ Wcl,
    const float* __restrict__ b1c, const float* __restrict__ W2c, const float* __restrict__ b2c,
    float* __restrict__ out){
  __shared__ short xs[2][32][264];
  __shared__ float ph[2][2][32];
  const int t = threadIdx.x;
  const int lane = t & 63, wv = t >> 6;
  const size_t v0 = (size_t)blockIdx.x * 32;

  {
    #pragma unroll
    for(int r=0; r<8; r++){
      int row = wv*8 + r;
      float4 v = *(const float4*)&Lh[(v0 + row)*256 + lane*4];
      unsigned short hx=f2b(v.x), hy=f2b(v.y), hz=f2b(v.z), hw=f2b(v.w);
      unsigned short lx=f2b(v.x-b2f(hx)), ly=f2b(v.y-b2f(hy));
      unsigned short lz=f2b(v.z-b2f(hz)), lw=f2b(v.w-b2f(hw));
      *(uint2*)&xs[0][row][lane*4] = make_uint2(((unsigned int)hy<<16)|hx, ((unsigned int)hw<<16)|hz);
      *(uint2*)&xs[1][row][lane*4] = make_uint2(((unsigned int)ly<<16)|lx, ((unsigned int)lw<<16)|lz);
    }
  }
  __syncthreads();

  const int hd = wv >> 1, nh = wv & 1;
  const short8* BH = (const short8*)(hd ? Wch : Wdh);
  const short8* BL = (const short8*)(hd ? Wcl : Wdl);
  const float* b1 = hd ? b1c : b1d;
  const float* w2 = hd ? W2c : W2d;
  const int am0 = (lane & 15), am1 = 16 + (lane & 15);
  const int ak = (lane >> 4) * 8;

  float part[2][4] = {{0.f,0.f,0.f,0.f},{0.f,0.f,0.f,0.f}};
  #pragma unroll
  for(int g2=0; g2<2; g2++){
    f32x4 acc[2][4];
    #pragma unroll
    for(int ntl=0; ntl<4; ntl++){
      float bv = b1[(nh*8 + g2*4 + ntl)*16 + (lane & 15)];
      acc[0][ntl] = (f32x4){bv, bv, bv, bv};
      acc[1][ntl] = acc[0][ntl];
    }
    #pragma unroll
    for(int kt=0; kt<8; kt++){
      short8 ah0 = *(const short8*)&xs[0][am0][kt*32 + ak];
      short8 al0 = *(const short8*)&xs[1][am0][kt*32 + ak];
      short8 ah1 = *(const short8*)&xs[0][am1][kt*32 + ak];
      short8 al1 = *(const short8*)&xs[1][am1][kt*32 + ak];
      #pragma unroll
      for(int ntl=0; ntl<4; ntl++){
        int g = nh*8 + g2*4 + ntl;
        short8 bh = BH[(g*8 + kt)*64 + lane];
        short8 bl = BL[(g*8 + kt)*64 + lane];
        acc[0][ntl] = __builtin_amdgcn_mfma_f32_16x16x32_bf16(ah0, bh, acc[0][ntl], 0, 0, 0);
        acc[0][ntl] = __builtin_amdgcn_mfma_f32_16x16x32_bf16(ah0, bl, acc[0][ntl], 0, 0, 0);
        acc[0][ntl] = __builtin_amdgcn_mfma_f32_16x16x32_bf16(al0, bh, acc[0][ntl], 0, 0, 0);
        acc[1][ntl] = __builtin_amdgcn_mfma_f32_16x16x32_bf16(ah1, bh, acc[1][ntl], 0, 0, 0);
        acc[1][ntl] = __builtin_amdgcn_mfma_f32_16x16x32_bf16(ah1, bl, acc[1][ntl], 0, 0, 0);
        acc[1][ntl] = __builtin_amdgcn_mfma_f32_16x16x32_bf16(al1, bh, acc[1][ntl], 0, 0, 0);
      }
    }
    #pragma unroll
    for(int ntl=0; ntl<4; ntl++){
      float wv2 = w2[(nh*8 + g2*4 + ntl)*16 + (lane & 15)];
      #pragma unroll
      for(int rt=0; rt<2; rt++)
        #pragma unroll
        for(int reg=0; reg<4; reg++)
          part[rt][reg] = fmaf(fmaxf(acc[rt][ntl][reg], 0.f), wv2, part[rt][reg]);
    }
  }
  #pragma unroll
  for(int rt=0; rt<2; rt++){
    #pragma unroll
    for(int reg=0; reg<4; reg++){
      float p = part[rt][reg];
      p += __shfl_xor(p, 1, 64);
      p += __shfl_xor(p, 2, 64);
      p += __shfl_xor(p, 4, 64);
      p += __shfl_xor(p, 8, 64);
      if((lane & 15) == 0) ph[hd][nh][rt*16 + (lane >> 4)*4 + reg] = p;
    }
  }
  __syncthreads();
  if(t < 64){
    int h2 = t >> 5, row = t & 31;
    out[(size_t)h2*NVAR + v0 + row] = ph[h2][0][row] + ph[h2][1][row] + (h2 ? b2c[0] : b2d[0]);
  }
}

__global__ __launch_bounds__(256) void k_head_c2(
    const float* __restrict__ C, const float* __restrict__ st,
    const short* __restrict__ Wh, const short* __restrict__ Wl,
    const float* __restrict__ b1, const float* __restrict__ W2, const float* __restrict__ b2,
    float* __restrict__ out){
  __shared__ short xs[2][32][136];
  __shared__ float ph[4][32];
  const int t = threadIdx.x;
  const int lane = t & 63, wv = t >> 6;
  const size_t c0 = (size_t)blockIdx.x * 32;

  {
    const int half = lane >> 5, f4 = (lane & 31) * 4;
    float4 mean4 = *(const float4*)&st[256+f4];
    float4 isd4  = *(const float4*)&st[384+f4];
    const int rb4 = wv*8 + half*4;
    #pragma unroll
    for(int i=0; i<4; i++){
      int row = rb4 + i;
      float4 v = *(const float4*)&C[(c0 + row)*128 + f4];
      v.x = (v.x - mean4.x)*isd4.x; v.y = (v.y - mean4.y)*isd4.y;
      v.z = (v.z - mean4.z)*isd4.z; v.w = (v.w - mean4.w)*isd4.w;
      unsigned short hx=f2b(v.x), hy=f2b(v.y), hz=f2b(v.z), hw=f2b(v.w);
      unsigned short lx=f2b(v.x-b2f(hx)), ly=f2b(v.y-b2f(hy));
      unsigned short lz=f2b(v.z-b2f(hz)), lw=f2b(v.w-b2f(hw));
      *(uint2*)&xs[0][row][f4] = make_uint2(((unsigned int)hy<<16)|hx, ((unsigned int)hw<<16)|hz);
      *(uint2*)&xs[1][row][f4] = make_uint2(((unsigned int)ly<<16)|lx, ((unsigned int)lw<<16)|lz);
    }
  }
  __syncthreads();

  const int am0 = (lane & 15), am1 = 16 + (lane & 15);
  const int ak = (lane >> 4) * 8;
  f32x4 acc[2][2];
  #pragma unroll
  for(int ntl=0; ntl<2; ntl++){
    float bv = b1[(wv*2+ntl)*16 + (lane & 15)];
    acc[0][ntl] = (f32x4){bv, bv, bv, bv};
    acc[1][ntl] = acc[0][ntl];
  }
  const short8* BH = (const short8*)Wh;
  const short8* BL = (const short8*)Wl;
  #pragma unroll
  for(int kt=0; kt<4; kt++){
    short8 ah0 = *(const short8*)&xs[0][am0][kt*32 + ak];
    short8 al0 = *(const short8*)&xs[1][am0][kt*32 + ak];
    short8 ah1 = *(const short8*)&xs[0][am1][kt*32 + ak];
    short8 al1 = *(const short8*)&xs[1][am1][kt*32 + ak];
    #pragma unroll
    for(int ntl=0; ntl<2; ntl++){
      int g = wv*2 + ntl;
      short8 bh = BH[(g*4 + kt)*64 + lane];
      short8 bl = BL[(g*4 + kt)*64 + lane];
      acc[0][ntl] = __builtin_amdgcn_mfma_f32_16x16x32_bf16(ah0, bh, acc[0][ntl], 0, 0, 0);
      acc[0][ntl] = __builtin_amdgcn_mfma_f32_16x16x32_bf16(ah0, bl, acc[0][ntl], 0, 0, 0);
      acc[0][ntl] = __builtin_amdgcn_mfma_f32_16x16x32_bf16(al0, bh, acc[0][ntl], 0, 0, 0);
      acc[1][ntl] = __builtin_amdgcn_mfma_f32_16x16x32_bf16(ah1, bh, acc[1][ntl], 0, 0, 0);
      acc[1][ntl] = __builtin_amdgcn_mfma_f32_16x16x32_bf16(ah1, bl, acc[1][ntl], 0, 0, 0);
      acc[1][ntl] = __builtin_amdgcn_mfma_f32_16x16x32_bf16(al1, bh, acc[1][ntl], 0, 0, 0);
    }
  }
  float part[2][4] = {{0.f,0.f,0.f,0.f},{0.f,0.f,0.f,0.f}};
  #pragma unroll
  for(int ntl=0; ntl<2; ntl++){
    float wv2 = W2[(wv*2+ntl)*16 + (lane & 15)];
    #pragma unroll
    for(int rt=0; rt<2; rt++)
      #pragma unroll
      for(int reg=0; reg<4; reg++)
        part[rt][reg] = fmaf(fmaxf(acc[rt][ntl][reg], 0.f), wv2, part[rt][reg]);
  }
  #pragma unroll
  for(int rt=0; rt<2; rt++){
    #pragma unroll
    for(int reg=0; reg<4; reg++){
      float p = part[rt][reg];
      p += __shfl_xor(p, 1, 64);
      p += __shfl_xor(p, 2, 64);
      p += __shfl_xor(p, 4, 64);
      p += __shfl_xor(p, 8, 64);
      if((lane & 15) == 0) ph[wv][rt*16 + (lane >> 4)*4 + reg] = p;
    }
  }
  __syncthreads();
  if(t < 32) out[c0 + t] = ((ph[0][t] + ph[1][t]) + ph[2][t]) + ph[3][t] + b2[0];
}

// ---------------------------------------------------------------- launch
extern "C" void kernel_launch(void* const* d_in, const int* in_sizes, int n_in,
                              void* d_out, int out_size, void* d_ws, size_t ws_size,
                              hipStream_t stream){
  const float* L0   = (const float*)d_in[0];
  const float* lng  = (const float*)d_in[1];
  const float* lnb  = (const float*)d_in[2];
  const float* CuW1 = (const float*)d_in[3];
  const float* Cub1 = (const float*)d_in[4];
  const float* CuW2 = (const float*)d_in[5];
  const float* Cub2 = (const float*)d_in[6];
  const float* LuW1 = (const float*)d_in[7];
  const float* Lub1 = (const float*)d_in[8];
  const float* LuW2 = (const float*)d_in[9];
  const float* Lub2 = (const float*)d_in[10];
  const float* VdW1 = (const float*)d_in[11];
  const float* Vdb1 = (const float*)d_in[12];
  const float* VdW2 = (const float*)d_in[13];
  const float* Vdb2 = (const float*)d_in[14];
  const float* VcW1 = (const float*)d_in[15];
  const float* Vcb1 = (const float*)d_in[16];
  const float* VcW2 = (const float*)d_in[17];
  const float* Vcb2 = (const float*)d_in[18];
  const float* CsW1 = (const float*)d_in[19];
  const float* Csb1 = (const float*)d_in[20];
  const float* CsW2 = (const float*)d_in[21];
  const float* Csb2 = (const float*)d_in[22];
  const int* cidx = (const int*)d_in[23];
  const int* lidx = (const int*)d_in[24];
  const int  ne   = in_sizes[23];

  float* ws   = (float*)d_ws;
  float* Lh   = ws;                        // 25,600,000 f32 (Lvar paired layout)
  float* C    = ws + 25600000;             // 38,400,000 f32 -> end 64,000,000
  float* st   = ws + 64000000;             // 512: mean|isd at +256/+384
  short* W1h  = (short*)(ws + 64000512);   // 65,536 bf16
  short* W1l  = (short*)(ws + 64033280);   // 65,536 bf16
  short* W2h  = (short*)(ws + 64066048);   // 32,768 bf16
  short* W2l  = (short*)(ws + 64082432);   // 32,768 bf16
  short* W3h  = (short*)(ws + 64098816);   // 16,384 bf16 (LuW1 hi)
  short* W3l  = (short*)(ws + 64107008);   // 16,384 bf16
  short* W4h  = (short*)(ws + 64115200);   // 16,384 bf16 (LuW2 hi)
  short* W4l  = (short*)(ws + 64123392);   // 16,384 bf16
  int*   ib   = (int*)(ws + 64131584);     // int region
  int*   Pc   = ib;                        // PAD_C = 300,032
  int*   Pl   = ib + PAD_C;                // PAD_L = 200,704
  int*   clit = ib + PAD_C + PAD_L;        // 1,000,000 (packed Lvar offsets)
  int*   lcl  = clit + 1000000;            // 1,000,000 (packed C offsets)
  int*   psum = lcl + 1000000;             // 512
  float* part = ws + 66632832;             // 2*512*128 = 131,072 f32 -> 66,763,904
  short* W5h  = (short*)(ws + 66763904);   // 65,536 bf16 (VdW1 hi)
  short* W5l  = (short*)(ws + 66796672);   // 65,536 bf16
  short* W6h  = (short*)(ws + 66829440);   // 65,536 bf16 (VcW1 hi)
  short* W6l  = (short*)(ws + 66862208);   // 65,536 bf16
  short* W7h  = (short*)(ws + 66894976);   // 16,384 bf16 (CsW1 hi)
  short* W7l  = (short*)(ws + 66903168);   // 16,384 bf16 -> ends 66,911,360
  float* out = (float*)d_out;              // fp32: drat|core|c_core

  k_init_lh4<<<25000, 256, 0, stream>>>((const float4*)L0, (float4*)Lh);
  k_pack_w<<<256, 256, 0, stream>>>(CuW1, W1h, W1l, 256, 256);
  k_pack_w<<<128, 256, 0, stream>>>(CuW2, W2h, W2l, 256, 128);
  k_pack_w<<<64, 256, 0, stream>>>(LuW1, W3h, W3l, 128, 128);
  k_pack_w<<<64, 256, 0, stream>>>(LuW2, W4h, W4l, 128, 128);
  k_pack_w<<<256, 256, 0, stream>>>(VdW1, W5h, W5l, 256, 256);
  k_pack_w<<<256, 256, 0, stream>>>(VcW1, W6h, W6l, 256, 256);
  k_pack_w<<<64, 256, 0, stream>>>(CsW1, W7h, W7l, 128, 128);

  // CSR build (counting sort both directions) + canonical intra-row order
  k_zero4<<<489, 256, 0, stream>>>((float4*)Pc, (PAD_C + PAD_L)/4);
  k_hist<<<(ne+255)/256, 256, 0, stream>>>(cidx, lidx, Pc, Pl, ne);
  k_scan_pass1<<<NB_C, 256, 0, stream>>>(Pc, psum);
  k_scan_pass2<<<1, 512, 0, stream>>>(psum, NB_C);
  k_scan_pass3<<<NB_C, 256, 0, stream>>>(Pc, psum);
  k_scan_pass1<<<NB_L, 256, 0, stream>>>(Pl, psum);
  k_scan_pass2<<<1, 512, 0, stream>>>(psum, NB_L);
  k_scan_pass3<<<NB_L, 256, 0, stream>>>(Pl, psum);
  k_fill<<<(ne+255)/256, 256, 0, stream>>>(cidx, lidx, Pc, Pl, clit, lcl, ne);
  k_sortmap<<<(NCL+255)/256, 256, 0, stream>>>(Pc, clit, lidx, NCL, 0);
  k_sortmap<<<(NLIT+255)/256, 256, 0, stream>>>(Pl, lcl, cidx, NLIT, 1);

  for(int hop=0; hop<4; hop++){
    k_clause_fused<<<4688, 512, 0, stream>>>(Pc, clit, Lh,
        W1h, W1l, Cub1, W2h, W2l, Cub2, C);
    k_colstats2<<<512, 256, 0, stream>>>(C, part);
    k_finstats<<<1, 512, 0, stream>>>(part, st);
    k_lit_fused<<<6250, 256, 0, stream>>>(Pl, lcl, C, st, W3h, W3l, Lub1,
        W4h, W4l, Lub2, lng, lnb, Lh);
  }

  k_head_v2<<<3125, 256, 0, stream>>>(Lh, W5h, W5l, Vdb1, VdW2, Vdb2, W6h, W6l, Vcb1, VcW2, Vcb2, out);
  k_head_c2<<<9375, 256, 0, stream>>>(C, st, W7h, W7l, Csb1, CsW2, Csb2, out + 200000);
}